// Round 9
// baseline (356.592 us; speedup 1.0000x reference)
//
#include <hip/hip_runtime.h>

#define IN_F   128
#define OUT_F  64
#define GR     64    // rows per GEMM block
#define HB     128   // histogram helper blocks fused into gemm dispatch
#define SB     2048  // SPMM blocks: 8/CU; waves own contiguous row chunks
#define SCATB  1024  // scatter blocks

typedef float  f32x4  __attribute__((ext_vector_type(4)));
typedef unsigned int u32x2 __attribute__((ext_vector_type(2)));

// ---- bf16 helpers (RNE) ----
__device__ __forceinline__ unsigned short f2bf(float f) {
    unsigned int u = __float_as_uint(f);
    u += 0x7fffu + ((u >> 16) & 1u);
    return (unsigned short)(u >> 16);
}
__device__ __forceinline__ float bf2f(unsigned short h) {
    return __uint_as_float(((unsigned int)h) << 16);
}

// ------- GEMM (+fused row histogram): out[n,o] = sum_k x[n,k]*W[o,k] + b[o] -------
// Helper blocks [gemm_blocks, gemm_blocks+HB) stream rowi and atomicAdd global
// rowcnt[row] (L2-served; ~16 adds/counter avg). rowcnt pre-zeroed by memset.
template <bool BF16OUT>
__global__ __launch_bounds__(256) void gemm_hist_kernel(
    const float* __restrict__ x, const float* __restrict__ W,
    const float* __restrict__ b, void* __restrict__ outv, int N,
    const int* __restrict__ rowi, int* __restrict__ rowcnt, int E,
    int gemm_blocks, int hist_blocks) {

    if ((int)blockIdx.x >= gemm_blocks) {
        int hb = blockIdx.x - gemm_blocks;
        for (int e = hb * 256 + threadIdx.x; e < E; e += hist_blocks * 256)
            atomicAdd(&rowcnt[rowi[e]], 1);
        return;
    }

    __shared__ float xs[GR][IN_F + 4];
    __shared__ float Wt[IN_F][OUT_F + 4];

    const int t = threadIdx.x;
    const int row0 = blockIdx.x * GR;

    for (int i = t; i < OUT_F * (IN_F / 4); i += 256) {
        int o = i & 63;
        int c = i >> 6;
        float4 v = ((const float4*)W)[o * (IN_F / 4) + c];
        Wt[4 * c + 0][o] = v.x;
        Wt[4 * c + 1][o] = v.y;
        Wt[4 * c + 2][o] = v.z;
        Wt[4 * c + 3][o] = v.w;
    }
    for (int i = t; i < GR * (IN_F / 4); i += 256) {
        int r = i >> 5, c = i & 31;
        int gr = row0 + r;
        float4 v = make_float4(0.f, 0.f, 0.f, 0.f);
        if (gr < N) v = ((const float4*)x)[(size_t)gr * (IN_F / 4) + c];
        *(float4*)&xs[r][4 * c] = v;
    }
    __syncthreads();

    const int f0 = (t & 15) * 4;
    const int r0 = (t >> 4) * 4;
    float acc[4][4] = {};

    #pragma unroll 2
    for (int k = 0; k < IN_F; k += 4) {
        float4 xv[4], wv[4];
        #pragma unroll
        for (int i = 0; i < 4; ++i) xv[i] = *(const float4*)&xs[r0 + i][k];
        #pragma unroll
        for (int j = 0; j < 4; ++j) wv[j] = *(const float4*)&Wt[k + j][f0];
        #pragma unroll
        for (int i = 0; i < 4; ++i) {
            #pragma unroll
            for (int j = 0; j < 4; ++j) {
                float wx = j == 0 ? wv[0].x : (j == 1 ? wv[0].y : (j == 2 ? wv[0].z : wv[0].w));
                float wy = j == 0 ? wv[1].x : (j == 1 ? wv[1].y : (j == 2 ? wv[1].z : wv[1].w));
                float wz = j == 0 ? wv[2].x : (j == 1 ? wv[2].y : (j == 2 ? wv[2].z : wv[2].w));
                float ww = j == 0 ? wv[3].x : (j == 1 ? wv[3].y : (j == 2 ? wv[3].z : wv[3].w));
                acc[i][j] = fmaf(xv[i].x, wx, acc[i][j]);
                acc[i][j] = fmaf(xv[i].y, wy, acc[i][j]);
                acc[i][j] = fmaf(xv[i].z, wz, acc[i][j]);
                acc[i][j] = fmaf(xv[i].w, ww, acc[i][j]);
            }
        }
    }

    float4 bv = *(const float4*)&b[f0];
    #pragma unroll
    for (int i = 0; i < 4; ++i) {
        int gr = row0 + r0 + i;
        if (gr < N) {
            float o0 = acc[i][0] + bv.x, o1 = acc[i][1] + bv.y;
            float o2 = acc[i][2] + bv.z, o3 = acc[i][3] + bv.w;
            if (BF16OUT) {
                ushort4 u = { f2bf(o0), f2bf(o1), f2bf(o2), f2bf(o3) };
                *(ushort4*)((unsigned short*)outv + (size_t)gr * OUT_F + f0) = u;
            } else {
                float4 o4 = make_float4(o0, o1, o2, o3);
                *(float4*)((float*)outv + (size_t)gr * OUT_F + f0) = o4;
            }
        }
    }
}

// ------- scan50k: exclusive scan of rowcnt[N] -> rowptr[N+1] and rowcur[N] -------
// One block, 1024 threads (16 waves). Thread t owns a contiguous chunk of VPT rows;
// two passes over rowcnt (2nd is L2-hot) avoid a runtime-indexed register array.
__global__ __launch_bounds__(1024) void scan50k_kernel(
    const int* __restrict__ rowcnt, int* __restrict__ rowptr,
    int* __restrict__ rowcur, int N, int E, int vpt) {
    const int t = threadIdx.x;
    const int base = t * vpt;
    int sum = 0;
    for (int i = 0; i < vpt; ++i) {
        int idx = base + i;
        if (idx < N) sum += rowcnt[idx];
    }
    // block exclusive scan of sum over 1024 threads
    int lane = t & 63, w = t >> 6;
    int s = sum;
    #pragma unroll
    for (int off = 1; off < 64; off <<= 1) {
        int xsh = __shfl_up(s, off, 64);
        if (lane >= off) s += xsh;
    }
    __shared__ int wsums[16];
    if (lane == 63) wsums[w] = s;
    __syncthreads();
    int woff = 0;
    for (int i = 0; i < w; ++i) woff += wsums[i];
    int run = s + woff - sum;              // exclusive prefix for this thread's chunk
    for (int i = 0; i < vpt; ++i) {
        int idx = base + i;
        if (idx < N) {
            rowptr[idx] = run;
            rowcur[idx] = run;
            run += rowcnt[idx];
        }
    }
    if (t == 1023) rowptr[N] = E;
}

// ------- scatter: direct CSR fill. pos = atomicAdd(rowcur[r]); scv[pos] = rec -------
// Random 4B writes land within the 3.2MB scv buffer (L2-absorbed); intra-row edge
// order is arbitrary (fp tolerance is loose; reference order is also unspecified).
__global__ __launch_bounds__(256) void scatter_kernel(
    const int* __restrict__ rowi, const int* __restrict__ coli,
    const float* __restrict__ attr, int* __restrict__ rowcur,
    unsigned int* __restrict__ scv, int E) {
    for (int e = blockIdx.x * 256 + threadIdx.x; e < E; e += gridDim.x * 256) {
        int r = rowi[e];
        unsigned int rec = ((unsigned int)coli[e] << 16) | (unsigned int)f2bf(attr[e]);
        int pos = atomicAdd(&rowcur[r], 1);
        scv[pos] = rec;
    }
}

// -------- SPMM (CSR): persistent waves, each owns a CONTIGUOUS chunk of rows --------
#define FMA4(w, p)                                              \
    a0 = fmaf((w), __uint_as_float((p).x << 16), a0);           \
    a1 = fmaf((w), __uint_as_float((p).x & 0xffff0000u), a1);   \
    a2 = fmaf((w), __uint_as_float((p).y << 16), a2);           \
    a3 = fmaf((w), __uint_as_float((p).y & 0xffff0000u), a3)

template <bool BF16OUT>
__global__ __launch_bounds__(256) void spmm_csr_kernel(
    const int* __restrict__ rowptr, const unsigned int* __restrict__ scv,
    const unsigned short* __restrict__ in, void* __restrict__ outv,
    int N, int nwaves) {
    int gw = (blockIdx.x * 256 + threadIdx.x) >> 6;   // global wave id
    int lane = threadIdx.x & 63;
    int rpw = (N + nwaves - 1) / nwaves;              // rows per wave (chunked)
    int r0 = gw * rpw;
    int r1 = r0 + rpw;
    if (r1 > N) r1 = N;
    const unsigned int g = lane >> 4;      // edge slot 0..3
    const unsigned int s = lane & 15;      // feature quad (features 4s..4s+3)

    for (int wr = r0; wr < r1; ++wr) {
        int wid = __builtin_amdgcn_readfirstlane(wr);
        int beg = rowptr[wid], end = rowptr[wid + 1];
        float a0 = 0.f, a1 = 0.f, a2 = 0.f, a3 = 0.f;

        int e = beg;
        for (; e + 16 <= end; e += 16) {
            unsigned int v0 = scv[e + g];
            unsigned int v1 = scv[e + 4 + g];
            unsigned int v2 = scv[e + 8 + g];
            unsigned int v3 = scv[e + 12 + g];
            u32x2 p0 = *(const u32x2*)(in + ((v0 >> 16) << 6) + (s << 2));
            u32x2 p1 = *(const u32x2*)(in + ((v1 >> 16) << 6) + (s << 2));
            u32x2 p2 = *(const u32x2*)(in + ((v2 >> 16) << 6) + (s << 2));
            u32x2 p3 = *(const u32x2*)(in + ((v3 >> 16) << 6) + (s << 2));
            float w0 = __uint_as_float(v0 << 16);
            float w1 = __uint_as_float(v1 << 16);
            float w2 = __uint_as_float(v2 << 16);
            float w3 = __uint_as_float(v3 << 16);
            FMA4(w0, p0);
            FMA4(w1, p1);
            FMA4(w2, p2);
            FMA4(w3, p3);
        }
        if (e + 8 <= end) {
            unsigned int v0 = scv[e + g];
            unsigned int v1 = scv[e + 4 + g];
            u32x2 p0 = *(const u32x2*)(in + ((v0 >> 16) << 6) + (s << 2));
            u32x2 p1 = *(const u32x2*)(in + ((v1 >> 16) << 6) + (s << 2));
            float w0 = __uint_as_float(v0 << 16);
            float w1 = __uint_as_float(v1 << 16);
            FMA4(w0, p0);
            FMA4(w1, p1);
            e += 8;
        }
        for (; e < end; e += 4) {
            unsigned int v = (e + (int)g < end) ? scv[e + g] : 0u;
            u32x2 p = *(const u32x2*)(in + ((v >> 16) << 6) + (s << 2));
            float w = __uint_as_float(v << 16);
            FMA4(w, p);
        }

        a0 += __shfl_xor(a0, 16); a0 += __shfl_xor(a0, 32);
        a1 += __shfl_xor(a1, 16); a1 += __shfl_xor(a1, 32);
        a2 += __shfl_xor(a2, 16); a2 += __shfl_xor(a2, 32);
        a3 += __shfl_xor(a3, 16); a3 += __shfl_xor(a3, 32);

        if (g == 0) {
            size_t o = (size_t)wid * OUT_F + (s << 2);
            if (BF16OUT) {
                unsigned long long u =  (unsigned long long)f2bf(a0)
                                     | ((unsigned long long)f2bf(a1) << 16)
                                     | ((unsigned long long)f2bf(a2) << 32)
                                     | ((unsigned long long)f2bf(a3) << 48);
                *(unsigned long long*)((unsigned short*)outv + o) = u;
            } else {
                f32x4 o4 = { a0, a1, a2, a3 };
                *(f32x4*)((float*)outv + o) = o4;
            }
        }
    }
}

// ---------------- fallback SPMM (fp32 atomics) if ws too small ----------------
__global__ __launch_bounds__(256) void spmm_atomic_kernel(
    const int* __restrict__ rowi, const int* __restrict__ coli,
    const float* __restrict__ attr, const float* __restrict__ in,
    float* __restrict__ out, int E) {
    int tid = blockIdx.x * 256 + threadIdx.x;
    int e = tid >> 6;
    int lane = tid & 63;
    if (e >= E) return;
    int r = rowi[e];
    int c = coli[e];
    float w = attr[e];
    float v = in[(size_t)c * OUT_F + lane];
    atomicAdd(&out[(size_t)r * OUT_F + lane], w * v);
}

extern "C" void kernel_launch(void* const* d_in, const int* in_sizes, int n_in,
                              void* d_out, int out_size, void* d_ws, size_t ws_size,
                              hipStream_t stream) {
    const float* x    = (const float*)d_in[0];
    const int*   ei   = (const int*)d_in[1];    // [2, E] int32
    const float* attr = (const float*)d_in[2];
    const float* W    = (const float*)d_in[3];
    const float* b    = (const float*)d_in[4];
    float* out = (float*)d_out;

    const int N = in_sizes[0] / IN_F;   // 50000
    const int E = in_sizes[2];          // 800000
    const int* rowi = ei;
    const int* coli = ei + E;

    const size_t obytes_f  = (size_t)N * OUT_F * sizeof(float);
    const size_t obytes_bf = (size_t)N * OUT_F * sizeof(unsigned short);

    // ---- ws layout ----
    char* wp = (char*)d_ws;
    size_t off = 0;
    auto alloc = [&](size_t bytes) { char* p = wp + off; off += (bytes + 255) & ~(size_t)255; return p; };
    unsigned short* bufA = (unsigned short*)alloc(obytes_bf);            // bf16 ping
    unsigned short* bufB = (unsigned short*)alloc(obytes_bf);            // bf16 pong
    int* rowptr  = (int*)alloc((size_t)(N + 1) * 4);
    int* rowcnt  = (int*)alloc((size_t)N * 4);
    int* rowcur  = (int*)alloc((size_t)N * 4);
    unsigned int* scv = (unsigned int*)alloc((size_t)E * 4);
    const bool csr_ok = (off <= ws_size) && (N <= 65535);

    const int gemm_blocks = (N + GR - 1) / GR;
    const int nwaves = SB * 4;

    if (csr_ok) {
        // ---- direct-scatter CSR build: memset -> gemm+hist -> scan -> scatter ----
        hipMemsetAsync(rowcnt, 0, (size_t)N * 4, stream);
        gemm_hist_kernel<true><<<gemm_blocks + HB, 256, 0, stream>>>(
            x, W, b, bufA, N, rowi, rowcnt, E, gemm_blocks, HB);
        const int vpt = (N + 1023) / 1024;
        scan50k_kernel<<<1, 1024, 0, stream>>>(rowcnt, rowptr, rowcur, N, E, vpt);
        scatter_kernel<<<SCATB, 256, 0, stream>>>(rowi, coli, attr, rowcur, scv, E);

        // ---- 3 rounds: bf16 -> bf16 -> bf16 -> fp32(d_out) ----
        spmm_csr_kernel<true ><<<SB, 256, 0, stream>>>(rowptr, scv, bufA, bufB, N, nwaves);
        spmm_csr_kernel<true ><<<SB, 256, 0, stream>>>(rowptr, scv, bufB, bufA, N, nwaves);
        spmm_csr_kernel<false><<<SB, 256, 0, stream>>>(rowptr, scv, bufA, out, N, nwaves);
    } else {
        // fallback: fp32 edge-parallel atomics, needs only one fp32 buffer
        float* ws0 = (float*)d_ws;
        gemm_hist_kernel<false><<<gemm_blocks, 256, 0, stream>>>(
            x, W, b, ws0, N, rowi, (int*)d_ws, 0, gemm_blocks, 0);
        const int spmm_blocks = (E * 64 + 255) / 256;
        hipMemsetAsync(out, 0, obytes_f, stream);
        spmm_atomic_kernel<<<spmm_blocks, 256, 0, stream>>>(rowi, coli, attr, ws0, out, E);
        hipMemsetAsync(ws0, 0, obytes_f, stream);
        spmm_atomic_kernel<<<spmm_blocks, 256, 0, stream>>>(rowi, coli, attr, out, ws0, E);
        hipMemsetAsync(out, 0, obytes_f, stream);
        spmm_atomic_kernel<<<spmm_blocks, 256, 0, stream>>>(rowi, coli, attr, ws0, out, E);
    }
}

// Round 10
// 185.635 us; speedup vs baseline: 1.9209x; 1.9209x over previous
//
#include <hip/hip_runtime.h>

#define IN_F   128
#define OUT_F  64
#define GR     64    // rows per GEMM block
#define EPB    2048  // edges per bin block (runs ~10 recs/bucket = 83B, still sector-scale)
#define HB     64    // histogram helper blocks fused into gemm dispatch (per-block partials)
#define SB     2048  // SPMM blocks: 8/CU, fully resident; waves grid-stride over row chunks

typedef float  f32x4  __attribute__((ext_vector_type(4)));
typedef unsigned int u32x2 __attribute__((ext_vector_type(2)));

// ---- bf16 helpers (RNE) ----
__device__ __forceinline__ unsigned short f2bf(float f) {
    unsigned int u = __float_as_uint(f);
    u += 0x7fffu + ((u >> 16) & 1u);
    return (unsigned short)(u >> 16);
}
__device__ __forceinline__ float bf2f(unsigned short h) {
    return __uint_as_float(((unsigned int)h) << 16);
}

// ------- GEMM (+fused bucket histogram): out[n,o] = sum_k x[n,k]*W[o,k] + b[o] -------
template <bool BF16OUT>
__global__ __launch_bounds__(256) void gemm_hist_kernel(
    const float* __restrict__ x, const float* __restrict__ W,
    const float* __restrict__ b, void* __restrict__ outv, int N,
    const int* __restrict__ rowi, int* __restrict__ bparts, int E,
    int gemm_blocks, int hist_blocks) {

    if ((int)blockIdx.x >= gemm_blocks) {
        __shared__ int hcnt[256];
        int t = threadIdx.x;
        hcnt[t] = 0;
        __syncthreads();
        int hb = blockIdx.x - gemm_blocks;
        for (int e = hb * 256 + t; e < E; e += hist_blocks * 256)
            atomicAdd(&hcnt[rowi[e] >> 8], 1);
        __syncthreads();
        bparts[hb * 256 + t] = hcnt[t];
        return;
    }

    __shared__ float xs[GR][IN_F + 4];
    __shared__ float Wt[IN_F][OUT_F + 4];

    const int t = threadIdx.x;
    const int row0 = blockIdx.x * GR;

    for (int i = t; i < OUT_F * (IN_F / 4); i += 256) {
        int o = i & 63;
        int c = i >> 6;
        float4 v = ((const float4*)W)[o * (IN_F / 4) + c];
        Wt[4 * c + 0][o] = v.x;
        Wt[4 * c + 1][o] = v.y;
        Wt[4 * c + 2][o] = v.z;
        Wt[4 * c + 3][o] = v.w;
    }
    for (int i = t; i < GR * (IN_F / 4); i += 256) {
        int r = i >> 5, c = i & 31;
        int gr = row0 + r;
        float4 v = make_float4(0.f, 0.f, 0.f, 0.f);
        if (gr < N) v = ((const float4*)x)[(size_t)gr * (IN_F / 4) + c];
        *(float4*)&xs[r][4 * c] = v;
    }
    __syncthreads();

    const int f0 = (t & 15) * 4;
    const int r0 = (t >> 4) * 4;
    float acc[4][4] = {};

    #pragma unroll 2
    for (int k = 0; k < IN_F; k += 4) {
        float4 xv[4], wv[4];
        #pragma unroll
        for (int i = 0; i < 4; ++i) xv[i] = *(const float4*)&xs[r0 + i][k];
        #pragma unroll
        for (int j = 0; j < 4; ++j) wv[j] = *(const float4*)&Wt[k + j][f0];
        #pragma unroll
        for (int i = 0; i < 4; ++i) {
            #pragma unroll
            for (int j = 0; j < 4; ++j) {
                float wx = j == 0 ? wv[0].x : (j == 1 ? wv[0].y : (j == 2 ? wv[0].z : wv[0].w));
                float wy = j == 0 ? wv[1].x : (j == 1 ? wv[1].y : (j == 2 ? wv[1].z : wv[1].w));
                float wz = j == 0 ? wv[2].x : (j == 1 ? wv[2].y : (j == 2 ? wv[2].z : wv[2].w));
                float ww = j == 0 ? wv[3].x : (j == 1 ? wv[3].y : (j == 2 ? wv[3].z : wv[3].w));
                acc[i][j] = fmaf(xv[i].x, wx, acc[i][j]);
                acc[i][j] = fmaf(xv[i].y, wy, acc[i][j]);
                acc[i][j] = fmaf(xv[i].z, wz, acc[i][j]);
                acc[i][j] = fmaf(xv[i].w, ww, acc[i][j]);
            }
        }
    }

    float4 bv = *(const float4*)&b[f0];
    #pragma unroll
    for (int i = 0; i < 4; ++i) {
        int gr = row0 + r0 + i;
        if (gr < N) {
            float o0 = acc[i][0] + bv.x, o1 = acc[i][1] + bv.y;
            float o2 = acc[i][2] + bv.z, o3 = acc[i][3] + bv.w;
            if (BF16OUT) {
                ushort4 u = { f2bf(o0), f2bf(o1), f2bf(o2), f2bf(o3) };
                *(ushort4*)((unsigned short*)outv + (size_t)gr * OUT_F + f0) = u;
            } else {
                float4 o4 = make_float4(o0, o1, o2, o3);
                *(float4*)((float*)outv + (size_t)gr * OUT_F + f0) = o4;
            }
        }
    }
}

// ------- Phase 2: sum partials (ILP-unrolled) + scan bucket counts (1 block) -------
__global__ __launch_bounds__(256) void bscan_kernel(const int* __restrict__ bparts,
                                                    int* __restrict__ bbase,
                                                    int* __restrict__ bcursor,
                                                    int* __restrict__ rowptr,
                                                    int nb, int N, int E) {
    int t = threadIdx.x;
    // HB=64 partials per bucket; 4 independent accumulators keep 4 loads in flight
    int a0 = 0, a1 = 0, a2 = 0, a3 = 0;
    if (t < nb) {
        #pragma unroll
        for (int hb = 0; hb < HB; hb += 4) {
            a0 += bparts[(hb + 0) * 256 + t];
            a1 += bparts[(hb + 1) * 256 + t];
            a2 += bparts[(hb + 2) * 256 + t];
            a3 += bparts[(hb + 3) * 256 + t];
        }
    }
    int v = (a0 + a1) + (a2 + a3);
    int lane = t & 63, w = t >> 6;
    int sum = v;
    #pragma unroll
    for (int off = 1; off < 64; off <<= 1) {
        int x = __shfl_up(sum, off, 64);
        if (lane >= off) sum += x;
    }
    __shared__ int wsum[4];
    if (lane == 63) wsum[w] = sum;
    __syncthreads();
    int woff = 0;
    for (int i = 0; i < w; ++i) woff += wsum[i];
    int excl = sum + woff - v;
    if (t <= nb) bbase[t] = excl;          // bbase[nb] = E
    if (t < nb)  bcursor[t] = excl;
    if (t == 0)  rowptr[N] = E;            // safety (also written by bsort when N%256 != 0)
}

// ---------------- Phase 3: bin edges into bucket segments (8B recs, chunked writes) ---------
// EPB=2048 -> 391 blocks (2x occupancy vs R5's 196); runs ~10 recs/bucket = 83B.
__global__ __launch_bounds__(512) void bin_kernel(
    const int* __restrict__ rowi, const int* __restrict__ coli,
    const float* __restrict__ attr, int* __restrict__ bcursor,
    unsigned long long* __restrict__ tmp, int E) {
    __shared__ int cnt[256];
    __shared__ int cur[256];
    __shared__ int gbase[256];
    int t = threadIdx.x;
    int e0 = blockIdx.x * EPB;
    if (t < 256) { cnt[t] = 0; cur[t] = 0; }
    __syncthreads();
    int myrow[4];
    #pragma unroll
    for (int i = 0; i < 4; ++i) {
        int e = e0 + i * 512 + t;
        myrow[i] = (e < E) ? rowi[e] : -1;
        if (myrow[i] >= 0) atomicAdd(&cnt[myrow[i] >> 8], 1);
    }
    __syncthreads();
    if (t < 256 && cnt[t] > 0) gbase[t] = atomicAdd(&bcursor[t], cnt[t]);
    __syncthreads();
    #pragma unroll
    for (int i = 0; i < 4; ++i) {
        int e = e0 + i * 512 + t;
        if (myrow[i] >= 0) {
            int b = myrow[i] >> 8;
            int rank = atomicAdd(&cur[b], 1);
            unsigned long long rec = ((unsigned long long)(myrow[i] & 255) << 32)
                                   | ((unsigned int)coli[e] << 16)
                                   | (unsigned int)f2bf(attr[e]);
            tmp[(size_t)gbase[b] + rank] = rec;
        }
    }
}

// ---------------- Phase 4: per-bucket sort -> scv + rowptr (1024 thr, uniform barriers) ----
__global__ __launch_bounds__(1024) void bsort_kernel(
    const unsigned long long* __restrict__ tmp, const int* __restrict__ bbase,
    unsigned int* __restrict__ scv, int* __restrict__ rowptr, int N) {
    __shared__ int cnt[256];
    __shared__ int cur[256];
    __shared__ int wsum[4];
    int t = threadIdx.x, b = blockIdx.x;
    int seg = bbase[b], segend = bbase[b + 1];
    if (t < 256) cnt[t] = 0;
    __syncthreads();
    for (int i = seg + t; i < segend; i += 1024)
        atomicAdd(&cnt[(int)(tmp[i] >> 32)], 1);
    __syncthreads();
    // scan over the 256 counters; all threads execute (writes predicated), barriers uniform
    int v = (t < 256) ? cnt[t] : 0;
    int lane = t & 63, w = t >> 6;
    int sum = v;
    #pragma unroll
    for (int off = 1; off < 64; off <<= 1) {
        int x = __shfl_up(sum, off, 64);
        if (lane >= off) sum += x;
    }
    if (lane == 63 && w < 4) wsum[w] = sum;
    __syncthreads();
    if (t < 256) {
        int woff = 0;
        for (int i = 0; i < w; ++i) woff += wsum[i];
        int excl = sum + woff - v;
        int gidx = b * 256 + t;
        if (gidx <= N) rowptr[gidx] = seg + excl;
        cur[t] = excl;
    }
    __syncthreads();
    for (int i = seg + t; i < segend; i += 1024) {
        unsigned long long rec = tmp[i];
        int rl = (int)(rec >> 32);
        int pos = atomicAdd(&cur[rl], 1);
        scv[(size_t)seg + pos] = (unsigned int)rec;   // random 4B within 16KB L2 window
    }
}

// -------- SPMM (CSR): persistent waves, each owns a CONTIGUOUS chunk of rows --------
#define FMA4(w, p)                                              \
    a0 = fmaf((w), __uint_as_float((p).x << 16), a0);           \
    a1 = fmaf((w), __uint_as_float((p).x & 0xffff0000u), a1);   \
    a2 = fmaf((w), __uint_as_float((p).y << 16), a2);           \
    a3 = fmaf((w), __uint_as_float((p).y & 0xffff0000u), a3)

template <bool BF16OUT>
__global__ __launch_bounds__(256) void spmm_csr_kernel(
    const int* __restrict__ rowptr, const unsigned int* __restrict__ scv,
    const unsigned short* __restrict__ in, void* __restrict__ outv,
    int N, int nwaves) {
    int gw = (blockIdx.x * 256 + threadIdx.x) >> 6;   // global wave id
    int lane = threadIdx.x & 63;
    int rpw = (N + nwaves - 1) / nwaves;              // rows per wave (chunked)
    int r0 = gw * rpw;
    int r1 = r0 + rpw;
    if (r1 > N) r1 = N;
    const unsigned int g = lane >> 4;      // edge slot 0..3
    const unsigned int s = lane & 15;      // feature quad (features 4s..4s+3)

    for (int wr = r0; wr < r1; ++wr) {
        int wid = __builtin_amdgcn_readfirstlane(wr);
        int beg = rowptr[wid], end = rowptr[wid + 1];
        float a0 = 0.f, a1 = 0.f, a2 = 0.f, a3 = 0.f;

        int e = beg;
        for (; e + 16 <= end; e += 16) {
            unsigned int v0 = scv[e + g];
            unsigned int v1 = scv[e + 4 + g];
            unsigned int v2 = scv[e + 8 + g];
            unsigned int v3 = scv[e + 12 + g];
            u32x2 p0 = *(const u32x2*)(in + ((v0 >> 16) << 6) + (s << 2));
            u32x2 p1 = *(const u32x2*)(in + ((v1 >> 16) << 6) + (s << 2));
            u32x2 p2 = *(const u32x2*)(in + ((v2 >> 16) << 6) + (s << 2));
            u32x2 p3 = *(const u32x2*)(in + ((v3 >> 16) << 6) + (s << 2));
            float w0 = __uint_as_float(v0 << 16);
            float w1 = __uint_as_float(v1 << 16);
            float w2 = __uint_as_float(v2 << 16);
            float w3 = __uint_as_float(v3 << 16);
            FMA4(w0, p0);
            FMA4(w1, p1);
            FMA4(w2, p2);
            FMA4(w3, p3);
        }
        if (e + 8 <= end) {
            unsigned int v0 = scv[e + g];
            unsigned int v1 = scv[e + 4 + g];
            u32x2 p0 = *(const u32x2*)(in + ((v0 >> 16) << 6) + (s << 2));
            u32x2 p1 = *(const u32x2*)(in + ((v1 >> 16) << 6) + (s << 2));
            float w0 = __uint_as_float(v0 << 16);
            float w1 = __uint_as_float(v1 << 16);
            FMA4(w0, p0);
            FMA4(w1, p1);
            e += 8;
        }
        for (; e < end; e += 4) {
            unsigned int v = (e + (int)g < end) ? scv[e + g] : 0u;
            u32x2 p = *(const u32x2*)(in + ((v >> 16) << 6) + (s << 2));
            float w = __uint_as_float(v << 16);
            FMA4(w, p);
        }

        a0 += __shfl_xor(a0, 16); a0 += __shfl_xor(a0, 32);
        a1 += __shfl_xor(a1, 16); a1 += __shfl_xor(a1, 32);
        a2 += __shfl_xor(a2, 16); a2 += __shfl_xor(a2, 32);
        a3 += __shfl_xor(a3, 16); a3 += __shfl_xor(a3, 32);

        if (g == 0) {
            size_t o = (size_t)wid * OUT_F + (s << 2);
            if (BF16OUT) {
                unsigned long long u =  (unsigned long long)f2bf(a0)
                                     | ((unsigned long long)f2bf(a1) << 16)
                                     | ((unsigned long long)f2bf(a2) << 32)
                                     | ((unsigned long long)f2bf(a3) << 48);
                *(unsigned long long*)((unsigned short*)outv + o) = u;
            } else {
                f32x4 o4 = { a0, a1, a2, a3 };
                *(f32x4*)((float*)outv + o) = o4;
            }
        }
    }
}

// ---------------- fallback SPMM (fp32 atomics) if ws too small ----------------
__global__ __launch_bounds__(256) void spmm_atomic_kernel(
    const int* __restrict__ rowi, const int* __restrict__ coli,
    const float* __restrict__ attr, const float* __restrict__ in,
    float* __restrict__ out, int E) {
    int tid = blockIdx.x * 256 + threadIdx.x;
    int e = tid >> 6;
    int lane = tid & 63;
    if (e >= E) return;
    int r = rowi[e];
    int c = coli[e];
    float w = attr[e];
    float v = in[(size_t)c * OUT_F + lane];
    atomicAdd(&out[(size_t)r * OUT_F + lane], w * v);
}

extern "C" void kernel_launch(void* const* d_in, const int* in_sizes, int n_in,
                              void* d_out, int out_size, void* d_ws, size_t ws_size,
                              hipStream_t stream) {
    const float* x    = (const float*)d_in[0];
    const int*   ei   = (const int*)d_in[1];    // [2, E] int32
    const float* attr = (const float*)d_in[2];
    const float* W    = (const float*)d_in[3];
    const float* b    = (const float*)d_in[4];
    float* out = (float*)d_out;

    const int N = in_sizes[0] / IN_F;   // 50000
    const int E = in_sizes[2];          // 800000
    const int* rowi = ei;
    const int* coli = ei + E;

    const size_t obytes_f  = (size_t)N * OUT_F * sizeof(float);
    const size_t obytes_bf = (size_t)N * OUT_F * sizeof(unsigned short);
    const int nb = (N + 255) / 256;     // 196 buckets

    // ---- ws layout (tmp overlays bufB: tmp dead before spmm round 1 writes bufB) ----
    char* wp = (char*)d_ws;
    size_t off = 0;
    auto alloc = [&](size_t bytes) { char* p = wp + off; off += (bytes + 255) & ~(size_t)255; return p; };
    unsigned short* bufA = (unsigned short*)alloc(obytes_bf);            // bf16 ping
    unsigned short* bufB = (unsigned short*)alloc((size_t)E * 8);        // bf16 pong / tmp overlay
    unsigned long long* tmp = (unsigned long long*)bufB;
    int* rowptr  = (int*)alloc((size_t)(N + 1) * 4);
    int* bparts  = (int*)alloc((size_t)HB * 256 * 4);
    int* bbase   = (int*)alloc(260 * 4);
    int* bcursor = (int*)alloc(260 * 4);
    unsigned int* scv = (unsigned int*)alloc((size_t)E * 4);
    const bool csr_ok = (off <= ws_size) && (N <= 65280) && ((size_t)E * 8 >= obytes_bf);

    const int gemm_blocks = (N + GR - 1) / GR;
    const int nwaves = SB * 4;

    if (csr_ok) {
        // ---- GEMM + fused histogram (per-block partials, no memset needed) ----
        gemm_hist_kernel<true><<<gemm_blocks + HB, 256, 0, stream>>>(
            x, W, b, bufA, N, rowi, bparts, E, gemm_blocks, HB);

        // ---- build row-sorted packed CSR via 2-phase bucketed counting sort ----
        bscan_kernel<<<1, 256, 0, stream>>>(bparts, bbase, bcursor, rowptr, nb, N, E);
        bin_kernel<<<(E + EPB - 1) / EPB, 512, 0, stream>>>(rowi, coli, attr, bcursor, tmp, E);
        bsort_kernel<<<nb, 1024, 0, stream>>>(tmp, bbase, scv, rowptr, N);

        // ---- 3 rounds: bf16 -> bf16 -> bf16 -> fp32(d_out); persistent-style waves ----
        spmm_csr_kernel<true ><<<SB, 256, 0, stream>>>(rowptr, scv, bufA, bufB, N, nwaves);
        spmm_csr_kernel<true ><<<SB, 256, 0, stream>>>(rowptr, scv, bufB, bufA, N, nwaves);
        spmm_csr_kernel<false><<<SB, 256, 0, stream>>>(rowptr, scv, bufA, out, N, nwaves);
    } else {
        // fallback: fp32 edge-parallel atomics, needs only one fp32 buffer
        float* ws0 = (float*)d_ws;
        gemm_hist_kernel<false><<<gemm_blocks, 256, 0, stream>>>(
            x, W, b, ws0, N, rowi, (int*)d_ws, 0, gemm_blocks, 0);
        const int spmm_blocks = (E * 64 + 255) / 256;
        hipMemsetAsync(out, 0, obytes_f, stream);
        spmm_atomic_kernel<<<spmm_blocks, 256, 0, stream>>>(rowi, coli, attr, ws0, out, E);
        hipMemsetAsync(ws0, 0, obytes_f, stream);
        spmm_atomic_kernel<<<spmm_blocks, 256, 0, stream>>>(rowi, coli, attr, out, ws0, E);
        hipMemsetAsync(out, 0, obytes_f, stream);
        spmm_atomic_kernel<<<spmm_blocks, 256, 0, stream>>>(rowi, coli, attr, ws0, out, E);
    }
}